// Round 8
// baseline (304.201 us; speedup 1.0000x reference)
//
#include <hip/hip_runtime.h>
#include <hip/hip_fp16.h>
#include <cmath>

typedef _Float16 f16x8 __attribute__((ext_vector_type(8)));
typedef _Float16 f16x4 __attribute__((ext_vector_type(4)));
typedef float f32x4 __attribute__((ext_vector_type(4)));

#define NV 32000
#define NE 256
#define NH 512
#define NB 64
#define NT 2048

__device__ __forceinline__ float fast_tanh(float x) {
  return 1.f - 2.f / (__expf(2.f * x) + 1.f);
}
__device__ __forceinline__ float fast_sig(float x) {
  return 1.f / (1.f + __expf(-x));
}

// ---------- Be fragment-swizzle (W_attn second half -> f16 frags) ----------
// layout [kc(16)][nt(32)][lane(64)][reg(8)]: B[h][n]=W_attn[n][512+h],
// h = kc*32 + (l>>4)*8 + reg, n = nt*16 + (l&15)
__global__ void k_swz_be(const float* __restrict__ Wattn, _Float16* __restrict__ Be) {
  int idx = blockIdx.x * 256 + threadIdx.x;   // 0..32767
  int l = idx & 63, nt = (idx >> 6) & 31, kc = idx >> 11;
  int n = (nt << 4) + (l & 15);
  int h0 = (kc << 5) + ((l >> 4) << 3);
  const float* s = Wattn + n * 1024 + 512 + h0;
  _Float16* d = Be + idx * 8;
  #pragma unroll
  for (int j = 0; j < 8; ++j) d[j] = (_Float16)s[j];
}

// ---------- htop f16 (+ xcat1 second half) ----------
__global__ void k_prep_htop(const float* __restrict__ h0, _Float16* __restrict__ xh,
                            _Float16* __restrict__ xcat1) {
  int b = blockIdx.x, t = threadIdx.x;   // 512 thr
  _Float16 v = (_Float16)h0[NB * NH + b * NH + t];
  xh[b * NH + t] = v;
  xcat1[b * 1024 + 512 + t] = v;
}

// ---------- generic MFMA GEMM: C_part[kcid] = A(f16 [64xK]) x B(f32 rows)^T ----------
template <int KLEN>
__global__ __launch_bounds__(128)
void k_gemm_bT(const _Float16* __restrict__ A, int K,
               const float* __restrict__ B0, int ldb0,
               const float* __restrict__ B1, int ldb1, int b1k,
               const float* __restrict__ bias,
               float* __restrict__ out, int N) {
  int ntiles = N >> 5;
  int bn = blockIdx.x % ntiles, kcid = blockIdx.x / ntiles;
  int tid = threadIdx.x, w = tid >> 6, l = tid & 63;
  int n = (bn << 5) + (w << 4) + (l & 15);
  int kq = (l >> 4) << 3;
  int k0 = kcid * KLEN;
  f32x4 acc[4];
  #pragma unroll
  for (int mi = 0; mi < 4; ++mi) acc[mi] = (f32x4){0.f, 0.f, 0.f, 0.f};
  #pragma unroll 2
  for (int kk = 0; kk < KLEN; kk += 32) {
    int kbase = k0 + kk;
    f16x8 a[4];
    #pragma unroll
    for (int mi = 0; mi < 4; ++mi)
      a[mi] = *(const f16x8*)(A + (size_t)((l & 15) + (mi << 4)) * K + kbase + kq);
    const float* bp;
    if (B1 && kbase >= b1k) bp = B1 + (size_t)n * ldb1 + (kbase - b1k) + kq;
    else                    bp = B0 + (size_t)n * ldb0 + kbase + kq;
    float4 x0 = *(const float4*)bp;
    float4 x1 = *(const float4*)(bp + 4);
    f16x8 bf = {(_Float16)x0.x, (_Float16)x0.y, (_Float16)x0.z, (_Float16)x0.w,
                (_Float16)x1.x, (_Float16)x1.y, (_Float16)x1.z, (_Float16)x1.w};
    #pragma unroll
    for (int mi = 0; mi < 4; ++mi)
      acc[mi] = __builtin_amdgcn_mfma_f32_16x16x32_f16(a[mi], bf, acc[mi], 0, 0, 0);
  }
  float* op = out + (size_t)kcid * 64 * N;
  #pragma unroll
  for (int mi = 0; mi < 4; ++mi)
    #pragma unroll
    for (int r = 0; r < 4; ++r) {
      int row = (mi << 4) + ((l >> 4) << 2) + r;
      float v = acc[mi][r];
      if (bias) v += bias[n];
      op[(size_t)row * N + n] = v;
    }
}

// ---------- fused energy + softmax partials + context partials ----------
// grid 2048, one 64x512 tile per block, 8 waves = (wm 0..1 row-half, wn 0..3
// col-group). NO LDS staging, NO barriers in K-loop: A-frags load straight
// from enc (f32x4 x2 + cvt), B-frags from preswizzled Be (L2-resident 512KB).
// acc[2][8]=64 VGPRs, no held staging regs -> fits 128-reg cap, no spill.
__global__ __launch_bounds__(512, 4)
void k_energy(const float* __restrict__ enc, const _Float16* __restrict__ Be,
              const float* __restrict__ hp0, const float* __restrict__ hp1,
              const float* __restrict__ battn, const float* __restrict__ vat,
              const int* __restrict__ mask,
              float* __restrict__ eng, float* __restrict__ mcsc,
              float* __restrict__ numpart) {
  __shared__ float hpl[NH], vl[NH], ep[64][4], wl[64], psc[4][NH];
  int tile = blockIdx.x;                // 0..2047
  int b = tile >> 5;
  long row0 = (long)tile << 6;
  int tid = threadIdx.x, w = tid >> 6, l = tid & 63;
  int wm = w >> 2, wn = w & 3;
  hpl[tid] = hp0[(b << 9) + tid] + hp1[(b << 9) + tid] + battn[tid];
  vl[tid] = vat[tid];
  __syncthreads();                      // hpl/vl visible

  // base for this lane's A-frag rows: row = wm*32 + (l&15) + mi*16
  const float* Ab = enc + (row0 + (wm << 5) + (l & 15)) * NH + ((l >> 4) << 3);
  f32x4 acc[2][8];
  #pragma unroll
  for (int mi = 0; mi < 2; ++mi)
    #pragma unroll
    for (int ni = 0; ni < 8; ++ni) acc[mi][ni] = (f32x4){0.f, 0.f, 0.f, 0.f};

  #pragma unroll 2
  for (int kc = 0; kc < 16; ++kc) {
    f16x8 afr[2];
    #pragma unroll
    for (int mi = 0; mi < 2; ++mi) {
      const float* ap = Ab + (size_t)(mi << 4) * NH + (kc << 5);
      f32x4 lo = *(const f32x4*)ap;
      f32x4 hi = *(const f32x4*)(ap + 4);
      afr[mi] = (f16x8){(_Float16)lo[0], (_Float16)lo[1],
                        (_Float16)lo[2], (_Float16)lo[3],
                        (_Float16)hi[0], (_Float16)hi[1],
                        (_Float16)hi[2], (_Float16)hi[3]};
    }
    #pragma unroll
    for (int ni = 0; ni < 8; ++ni) {
      f16x8 bfr = *(const f16x8*)(Be +
          (size_t)((((kc << 5) + (wn << 3) + ni) << 6) + l) * 8);
      acc[0][ni] = __builtin_amdgcn_mfma_f32_16x16x32_f16(afr[0], bfr, acc[0][ni], 0, 0, 0);
      acc[1][ni] = __builtin_amdgcn_mfma_f32_16x16x32_f16(afr[1], bfr, acc[1][ni], 0, 0, 0);
    }
  }

  // epilogue: ep[row][wn] = sum over this wave's 128 cols of v*tanh(acc+hp)
  int cl = l & 15;
  #pragma unroll
  for (int mi = 0; mi < 2; ++mi) {
    float s0 = 0.f, s1 = 0.f, s2 = 0.f, s3 = 0.f;
    #pragma unroll
    for (int ni = 0; ni < 8; ++ni) {
      int col = (wn << 7) + (ni << 4) + cl;
      float hv = hpl[col], vv = vl[col];
      s0 += vv * fast_tanh(acc[mi][ni][0] + hv);
      s1 += vv * fast_tanh(acc[mi][ni][1] + hv);
      s2 += vv * fast_tanh(acc[mi][ni][2] + hv);
      s3 += vv * fast_tanh(acc[mi][ni][3] + hv);
    }
    #pragma unroll
    for (int off = 1; off < 16; off <<= 1) {
      s0 += __shfl_xor(s0, off, 64);
      s1 += __shfl_xor(s1, off, 64);
      s2 += __shfl_xor(s2, off, 64);
      s3 += __shfl_xor(s3, off, 64);
    }
    if (cl == 0) {
      int rb = (wm << 5) + (mi << 4) + ((l >> 4) << 2);
      ep[rb][wn] = s0; ep[rb + 1][wn] = s1; ep[rb + 2][wn] = s2; ep[rb + 3][wn] = s3;
    }
  }
  __syncthreads();                      // ep complete

  // finalize (all waves redundantly, identical values): e, m, s, wl
  {
    float4 e4 = *(const float4*)&ep[l][0];
    float e = (e4.x + e4.y) + (e4.z + e4.w);
    int mk = mask[row0 + l];
    e = mk ? e : -3.0e38f;
    if (w == 0) eng[row0 + l] = e;
    float m = e;
    #pragma unroll
    for (int off = 32; off; off >>= 1) m = fmaxf(m, __shfl_xor(m, off, 64));
    float wv = mk ? __expf(e - m) : 0.f;
    float s = wv;
    #pragma unroll
    for (int off = 32; off; off >>= 1) s += __shfl_xor(s, off, 64);
    wl[l] = wv;                         // own-wave write covers own-wave reads
    if (tid == 0) { mcsc[tile * 2] = m; mcsc[tile * 2 + 1] = s; }
  }

  // ctx partial from global (tile L2-hot): rg row-group x 4 cols per thread
  {
    int rg = tid >> 7, j4 = tid & 127;
    const float* gp = enc + (row0 + (rg << 4)) * NH + (j4 << 2);
    float c0a = 0.f, c1a = 0.f, c2a = 0.f, c3a = 0.f;
    #pragma unroll 4
    for (int r16 = 0; r16 < 16; ++r16) {
      float4 ev = *(const float4*)(gp + (size_t)r16 * NH);
      float wv = wl[(rg << 4) + r16];
      c0a += wv * ev.x; c1a += wv * ev.y; c2a += wv * ev.z; c3a += wv * ev.w;
    }
    *(float4*)&psc[rg][j4 << 2] = (float4){c0a, c1a, c2a, c3a};
  }
  __syncthreads();                      // psc complete

  numpart[(size_t)tile * NH + tid] =
      psc[0][tid] + psc[1][tid] + psc[2][tid] + psc[3][tid];
}

// ---------- combine: softmax rebuild -> ctx, attn_weights, xcat0 ----------
__global__ void k_combine(const float* __restrict__ mcsc, const float* __restrict__ numpart,
                          const float* __restrict__ eng, const int* __restrict__ token,
                          const float* __restrict__ emb, const float* __restrict__ h0,
                          _Float16* __restrict__ xcat0, float* __restrict__ attw) {
  __shared__ float scale_s[32], Ms, dens;
  int b = blockIdx.x, tid = threadIdx.x;   // 512 thr
  if (tid < 32) {
    float m = mcsc[(b * 32 + tid) * 2];
    float s = mcsc[(b * 32 + tid) * 2 + 1];
    float M = m;
    #pragma unroll
    for (int off = 16; off; off >>= 1) M = fmaxf(M, __shfl_xor(M, off, 32));
    float sc = __expf(m - M);
    float d = sc * s;
    #pragma unroll
    for (int off = 16; off; off >>= 1) d += __shfl_xor(d, off, 32);
    scale_s[tid] = sc;
    if (tid == 0) { Ms = M; dens = d; }
  }
  __syncthreads();
  float M = Ms, rden = 1.f / dens;
  float a = 0.f;
  #pragma unroll 4
  for (int c = 0; c < 32; ++c) a += scale_s[c] * numpart[(size_t)(b * 32 + c) * NH + tid];
  xcat0[b * 1280 + 256 + tid] = (_Float16)(a * rden);
  if (tid < 256) xcat0[b * 1280 + tid] = (_Float16)emb[(size_t)token[b] * NE + tid];
  xcat0[b * 1280 + 768 + tid] = (_Float16)h0[b * NH + tid];
  #pragma unroll
  for (int i = 0; i < 4; ++i) {
    int t = tid + (i << 9);
    attw[(b << 11) + t] = __expf(eng[(b << 11) + t] - M) * rden;
  }
}

// ---------- LSTM cell activation (combines gate partials) ----------
__global__ void k_act(const float* __restrict__ pg, const float* __restrict__ bih,
                      const float* __restrict__ bhh, const float* __restrict__ cprev,
                      float* __restrict__ hout, float* __restrict__ cout,
                      _Float16* __restrict__ hf16, int hpitch, int nchunks) {
  int idx = blockIdx.x * 256 + threadIdx.x;   // 0..32767
  int b = idx >> 9, u = idx & 511;
  float g[4];
  #pragma unroll
  for (int gi = 0; gi < 4; ++gi) {
    float s = bih[gi * 512 + u] + bhh[gi * 512 + u];
    for (int kc = 0; kc < nchunks; ++kc)
      s += pg[((size_t)kc * 64 + b) * 2048 + gi * 512 + u];
    g[gi] = s;
  }
  float c = fast_sig(g[1]) * cprev[idx] + fast_sig(g[0]) * fast_tanh(g[2]);
  float h = fast_sig(g[3]) * fast_tanh(c);
  cout[idx] = c;
  hout[idx] = h;
  hf16[b * hpitch + u] = (_Float16)h;
}

// ---------- launch ----------
extern "C" void kernel_launch(void* const* d_in, const int* in_sizes, int n_in,
                              void* d_out, int out_size, void* d_ws, size_t ws_size,
                              hipStream_t stream) {
  (void)in_sizes; (void)n_in; (void)out_size; (void)ws_size;
  const int*   token = (const int*)d_in[0];
  const float* h0    = (const float*)d_in[1];
  const float* c0    = (const float*)d_in[2];
  const float* enc   = (const float*)d_in[3];
  const int*   mask  = (const int*)d_in[4];
  const float* emb   = (const float*)d_in[5];
  const float* Wattn = (const float*)d_in[6];
  const float* battn = (const float*)d_in[7];
  const float* vattn = (const float*)d_in[8];
  const float* Wih0  = (const float*)d_in[9];
  const float* Whh0  = (const float*)d_in[10];
  const float* bih0  = (const float*)d_in[11];
  const float* bhh0  = (const float*)d_in[12];
  const float* Wih1  = (const float*)d_in[13];
  const float* Whh1  = (const float*)d_in[14];
  const float* bih1  = (const float*)d_in[15];
  const float* bhh1  = (const float*)d_in[16];
  const float* Wout  = (const float*)d_in[17];
  const float* bout  = (const float*)d_in[18];

  float* ws    = (float*)d_ws;
  float* pghp  = ws;                       //  2*64*512
  float* eng   = pghp + 65536;             //  131072
  float* mcsc  = eng + 131072;             //  4096
  float* np    = mcsc + 4096;              //  2048*512
  float* pg0   = np + 1048576;             //  4*64*2048
  float* pg1   = pg0 + 524288;
  _Float16* Be    = (_Float16*)(pg1 + 524288);
  _Float16* xh    = Be + 262144;
  _Float16* xcat0 = xh + 32768;
  _Float16* xcat1 = xcat0 + 81920;
  _Float16* h1f   = xcat1 + 65536;

  float* out    = (float*)d_out;
  float* logits = out;
  float* hnew   = out + (size_t)NB * NV;
  float* cnew   = hnew + 2 * NB * NH;
  float* attw   = cnew + 2 * NB * NH;

  k_swz_be<<<dim3(128), dim3(256), 0, stream>>>(Wattn, Be);
  k_prep_htop<<<dim3(64), dim3(512), 0, stream>>>(h0, xh, xcat1);
  k_gemm_bT<256><<<dim3(32), dim3(128), 0, stream>>>(
      xh, NH, Wattn, 1024, nullptr, 0, 1 << 30, nullptr, pghp, NH);
  k_energy<<<dim3(2048), dim3(512), 0, stream>>>(
      enc, Be, pghp, pghp + 32768, battn, vattn, mask, eng, mcsc, np);
  k_combine<<<dim3(64), dim3(512), 0, stream>>>(
      mcsc, np, eng, token, emb, h0, xcat0, attw);
  k_gemm_bT<320><<<dim3(256), dim3(128), 0, stream>>>(
      xcat0, 1280, Wih0, 768, Whh0, NH, 768, nullptr, pg0, 2048);
  k_act<<<dim3(128), dim3(256), 0, stream>>>(
      pg0, bih0, bhh0, c0, hnew, cnew, xcat1, 1024, 4);
  k_gemm_bT<256><<<dim3(256), dim3(128), 0, stream>>>(
      xcat1, 1024, Wih1, NH, Whh1, NH, NH, nullptr, pg1, 2048);
  k_act<<<dim3(128), dim3(256), 0, stream>>>(
      pg1, bih1, bhh1, c0 + NB * NH, hnew + NB * NH, cnew + NB * NH, h1f, 512, 4);
  k_gemm_bT<512><<<dim3(1000), dim3(128), 0, stream>>>(
      h1f, NH, Wout, NH, nullptr, 0, 1 << 30, bout, logits, NV);
}

// Round 9
// 221.082 us; speedup vs baseline: 1.3760x; 1.3760x over previous
//
#include <hip/hip_runtime.h>
#include <hip/hip_fp16.h>
#include <cmath>

typedef _Float16 f16x8 __attribute__((ext_vector_type(8)));
typedef _Float16 f16x4 __attribute__((ext_vector_type(4)));
typedef float f32x4 __attribute__((ext_vector_type(4)));

#define NV 32000
#define NE 256
#define NH 512
#define NB 64
#define NT 2048

__device__ __forceinline__ float fast_tanh(float x) {
  return 1.f - 2.f / (__expf(2.f * x) + 1.f);
}
__device__ __forceinline__ float fast_sig(float x) {
  return 1.f / (1.f + __expf(-x));
}

// ---------- Be fragment-swizzle (W_attn second half -> f16 frags) ----------
// layout [kc(16)][nt(32)][lane(64)][reg(8)]: B[h][n]=W_attn[n][512+h],
// h = kc*32 + (l>>4)*8 + reg, n = nt*16 + (l&15)
__global__ void k_swz_be(const float* __restrict__ Wattn, _Float16* __restrict__ Be) {
  int idx = blockIdx.x * 256 + threadIdx.x;   // 0..32767
  int l = idx & 63, nt = (idx >> 6) & 31, kc = idx >> 11;
  int n = (nt << 4) + (l & 15);
  int h0 = (kc << 5) + ((l >> 4) << 3);
  const float* s = Wattn + n * 1024 + 512 + h0;
  _Float16* d = Be + idx * 8;
  #pragma unroll
  for (int j = 0; j < 8; ++j) d[j] = (_Float16)s[j];
}

// ---------- htop f16 (+ xcat1 second half) ----------
__global__ void k_prep_htop(const float* __restrict__ h0, _Float16* __restrict__ xh,
                            _Float16* __restrict__ xcat1) {
  int b = blockIdx.x, t = threadIdx.x;   // 512 thr
  _Float16 v = (_Float16)h0[NB * NH + b * NH + t];
  xh[b * NH + t] = v;
  xcat1[b * 1024 + 512 + t] = v;
}

// ---------- generic MFMA GEMM: C_part[kcid] = A(f16 [64xK]) x B(f32 rows)^T ----------
template <int KLEN>
__global__ __launch_bounds__(128)
void k_gemm_bT(const _Float16* __restrict__ A, int K,
               const float* __restrict__ B0, int ldb0,
               const float* __restrict__ B1, int ldb1, int b1k,
               const float* __restrict__ bias,
               float* __restrict__ out, int N) {
  int ntiles = N >> 5;
  int bn = blockIdx.x % ntiles, kcid = blockIdx.x / ntiles;
  int tid = threadIdx.x, w = tid >> 6, l = tid & 63;
  int n = (bn << 5) + (w << 4) + (l & 15);
  int kq = (l >> 4) << 3;
  int k0 = kcid * KLEN;
  f32x4 acc[4];
  #pragma unroll
  for (int mi = 0; mi < 4; ++mi) acc[mi] = (f32x4){0.f, 0.f, 0.f, 0.f};
  #pragma unroll 2
  for (int kk = 0; kk < KLEN; kk += 32) {
    int kbase = k0 + kk;
    f16x8 a[4];
    #pragma unroll
    for (int mi = 0; mi < 4; ++mi)
      a[mi] = *(const f16x8*)(A + (size_t)((l & 15) + (mi << 4)) * K + kbase + kq);
    const float* bp;
    if (B1 && kbase >= b1k) bp = B1 + (size_t)n * ldb1 + (kbase - b1k) + kq;
    else                    bp = B0 + (size_t)n * ldb0 + kbase + kq;
    float4 x0 = *(const float4*)bp;
    float4 x1 = *(const float4*)(bp + 4);
    f16x8 bf = {(_Float16)x0.x, (_Float16)x0.y, (_Float16)x0.z, (_Float16)x0.w,
                (_Float16)x1.x, (_Float16)x1.y, (_Float16)x1.z, (_Float16)x1.w};
    #pragma unroll
    for (int mi = 0; mi < 4; ++mi)
      acc[mi] = __builtin_amdgcn_mfma_f32_16x16x32_f16(a[mi], bf, acc[mi], 0, 0, 0);
  }
  float* op = out + (size_t)kcid * 64 * N;
  #pragma unroll
  for (int mi = 0; mi < 4; ++mi)
    #pragma unroll
    for (int r = 0; r < 4; ++r) {
      int row = (mi << 4) + ((l >> 4) << 2) + r;
      float v = acc[mi][r];
      if (bias) v += bias[n];
      op[(size_t)row * N + n] = v;
    }
}

// ---------- fused energy + softmax partials + context partials ----------
// grid 4096, one 32x512 tile per block, 256 thr (4 waves), ~39 KB LDS ->
// ~4 blocks/CU (16-wave register class, 4 INDEPENDENT blocks for overlap).
// r7 schedule minus the register-held early-issue (its spill source):
// stage h0 -> sync -> mfma h0 -> stage h1 (load->write immediate, disjoint
// LDS region) -> sync -> mfma h1 -> epilogue -> sync -> finalize -> ctx ->
// sync -> numpart. As rows 1024B, XOR-swizzle byte ^= (r&7)<<4.
__global__ __launch_bounds__(256, 4)
void k_energy(const float* __restrict__ enc, const _Float16* __restrict__ Be,
              const float* __restrict__ hp0, const float* __restrict__ hp1,
              const float* __restrict__ battn, const float* __restrict__ vat,
              const int* __restrict__ mask,
              float* __restrict__ eng, float* __restrict__ mcsc,
              float* __restrict__ numpart) {
  __shared__ _Float16 As[32 * 512];     // 32 KB, 1024B rows, swizzled
  __shared__ _Float16 hplh[NH], vlh[NH];
  __shared__ float ep[32][4], wl[32], psc[2][NH];
  int tile = blockIdx.x;                // 0..4095
  int b = tile >> 6;                    // 64 tiles per batch row
  long row0 = (long)tile << 5;
  int tid = threadIdx.x, w = tid >> 6, l = tid & 63;
  #pragma unroll
  for (int i = 0; i < 2; ++i) {
    int c = tid + (i << 8);
    hplh[c] = (_Float16)(hp0[(b << 9) + c] + hp1[(b << 9) + c] + battn[c]);
    vlh[c] = (_Float16)vat[c];
  }

  const float4* encp = (const float4*)(enc + row0 * NH);
  float4 rs[8];
  // stage half 0 (k 0..255): load 8 float4, write immediately
  #pragma unroll
  for (int i = 0; i < 8; ++i) {
    int s = tid + (i << 8);
    rs[i] = encp[(s >> 6) * 128 + (s & 63)];
  }
  #pragma unroll
  for (int i = 0; i < 8; ++i) {
    int s = tid + (i << 8);
    int r = s >> 6, c4 = s & 63;
    f16x4 h4 = {(_Float16)rs[i].x, (_Float16)rs[i].y,
                (_Float16)rs[i].z, (_Float16)rs[i].w};
    *(f16x4*)((char*)As + (r << 10) + ((c4 << 3) ^ ((r & 7) << 4))) = h4;
  }

  f32x4 acc[2][8];
  #pragma unroll
  for (int mi = 0; mi < 2; ++mi)
    #pragma unroll
    for (int ni = 0; ni < 8; ++ni) acc[mi][ni] = (f32x4){0.f, 0.f, 0.f, 0.f};

  __syncthreads();                      // half0 + hplh/vlh visible
  #pragma unroll
  for (int kc = 0; kc < 8; ++kc) {
    f16x8 afr[2];
    #pragma unroll
    for (int mi = 0; mi < 2; ++mi) {
      int r = (mi << 4) + (l & 15);
      afr[mi] = *(const f16x8*)((char*)As + (r << 10) +
                 (((kc << 6) + ((l >> 4) << 4)) ^ ((r & 7) << 4)));
    }
    #pragma unroll
    for (int ni = 0; ni < 8; ++ni) {
      f16x8 bfr = *(const f16x8*)(Be +
          (size_t)((((kc << 5) + (w << 3) + ni) << 6) + l) * 8);
      #pragma unroll
      for (int mi = 0; mi < 2; ++mi)
        acc[mi][ni] = __builtin_amdgcn_mfma_f32_16x16x32_f16(afr[mi], bfr,
                                                             acc[mi][ni], 0, 0, 0);
    }
  }
  // stage half 1 (k 256..511): load->write immediate; disjoint LDS bytes
  // from half0 frag reads, so no barrier needed before the writes
  #pragma unroll
  for (int i = 0; i < 8; ++i) {
    int s = tid + (i << 8);
    rs[i] = encp[(s >> 6) * 128 + 64 + (s & 63)];
  }
  #pragma unroll
  for (int i = 0; i < 8; ++i) {
    int s = tid + (i << 8);
    int r = s >> 6, c4 = s & 63;
    f16x4 h4 = {(_Float16)rs[i].x, (_Float16)rs[i].y,
                (_Float16)rs[i].z, (_Float16)rs[i].w};
    *(f16x4*)((char*)As + (r << 10) + ((512 + (c4 << 3)) ^ ((r & 7) << 4))) = h4;
  }
  __syncthreads();                      // half1 visible
  #pragma unroll
  for (int kc = 8; kc < 16; ++kc) {
    f16x8 afr[2];
    #pragma unroll
    for (int mi = 0; mi < 2; ++mi) {
      int r = (mi << 4) + (l & 15);
      afr[mi] = *(const f16x8*)((char*)As + (r << 10) +
                 (((kc << 6) + ((l >> 4) << 4)) ^ ((r & 7) << 4)));
    }
    #pragma unroll
    for (int ni = 0; ni < 8; ++ni) {
      f16x8 bfr = *(const f16x8*)(Be +
          (size_t)((((kc << 5) + (w << 3) + ni) << 6) + l) * 8);
      #pragma unroll
      for (int mi = 0; mi < 2; ++mi)
        acc[mi][ni] = __builtin_amdgcn_mfma_f32_16x16x32_f16(afr[mi], bfr,
                                                             acc[mi][ni], 0, 0, 0);
    }
  }

  // epilogue: ep[row][wave] = sum over wave's 128 cols of v*tanh(acc+hp)
  int cl = l & 15;
  #pragma unroll
  for (int mi = 0; mi < 2; ++mi) {
    float s0 = 0.f, s1 = 0.f, s2 = 0.f, s3 = 0.f;
    #pragma unroll
    for (int ni = 0; ni < 8; ++ni) {
      int col = (w << 7) + (ni << 4) + cl;
      float hv = (float)hplh[col], vv = (float)vlh[col];
      s0 += vv * fast_tanh(acc[mi][ni][0] + hv);
      s1 += vv * fast_tanh(acc[mi][ni][1] + hv);
      s2 += vv * fast_tanh(acc[mi][ni][2] + hv);
      s3 += vv * fast_tanh(acc[mi][ni][3] + hv);
    }
    #pragma unroll
    for (int off = 1; off < 16; off <<= 1) {
      s0 += __shfl_xor(s0, off, 64);
      s1 += __shfl_xor(s1, off, 64);
      s2 += __shfl_xor(s2, off, 64);
      s3 += __shfl_xor(s3, off, 64);
    }
    if (cl == 0) {
      int rb = (mi << 4) + ((l >> 4) << 2);
      ep[rb][w] = s0; ep[rb + 1][w] = s1; ep[rb + 2][w] = s2; ep[rb + 3][w] = s3;
    }
  }
  __syncthreads();                      // ep complete

  // finalize (all waves redundantly): energies, m/s, weights wl
  {
    int r = l & 31;
    float4 e4 = *(const float4*)&ep[r][0];
    float e = (e4.x + e4.y) + (e4.z + e4.w);
    int mk = mask[row0 + r];
    e = mk ? e : -3.0e38f;
    if (tid < 32) eng[row0 + tid] = e;
    float m = e;
    #pragma unroll
    for (int off = 16; off; off >>= 1) m = fmaxf(m, __shfl_xor(m, off, 64));
    float wv = mk ? __expf(e - m) : 0.f;
    float s = wv;
    #pragma unroll
    for (int off = 16; off; off >>= 1) s += __shfl_xor(s, off, 64);
    wl[r] = wv;                         // own-wave write covers own-wave reads
    if (tid == 0) { mcsc[tile * 2] = m; mcsc[tile * 2 + 1] = s; }
  }

  // ctx partial: thread (rg=tid>>7, j4=tid&127) handles 16 rows x 4 cols
  {
    int rg = tid >> 7, j4 = tid & 127;
    float c0a = 0.f, c1a = 0.f, c2a = 0.f, c3a = 0.f;
    #pragma unroll 4
    for (int r16 = 0; r16 < 16; ++r16) {
      int t = (rg << 4) + r16;
      f16x4 hv = *(const f16x4*)((char*)As + (t << 10) +
                                 ((j4 << 3) ^ ((t & 7) << 4)));
      float wv = wl[t];
      c0a += wv * (float)hv[0]; c1a += wv * (float)hv[1];
      c2a += wv * (float)hv[2]; c3a += wv * (float)hv[3];
    }
    *(float4*)&psc[rg][j4 << 2] = (float4){c0a, c1a, c2a, c3a};
  }
  __syncthreads();                      // psc complete

  numpart[(size_t)tile * NH + tid]       = psc[0][tid] + psc[1][tid];
  numpart[(size_t)tile * NH + 256 + tid] = psc[0][256 + tid] + psc[1][256 + tid];
}

// ---------- combine: softmax rebuild -> ctx, attn_weights, xcat0 ----------
__global__ void k_combine(const float* __restrict__ mcsc, const float* __restrict__ numpart,
                          const float* __restrict__ eng, const int* __restrict__ token,
                          const float* __restrict__ emb, const float* __restrict__ h0,
                          _Float16* __restrict__ xcat0, float* __restrict__ attw) {
  __shared__ float scale_s[64], Ms, dens;
  int b = blockIdx.x, tid = threadIdx.x;   // 512 thr
  if (tid < 64) {
    float m = mcsc[(b * 64 + tid) * 2];
    float s = mcsc[(b * 64 + tid) * 2 + 1];
    float M = m;
    #pragma unroll
    for (int off = 32; off; off >>= 1) M = fmaxf(M, __shfl_xor(M, off, 64));
    float sc = __expf(m - M);
    float d = sc * s;
    #pragma unroll
    for (int off = 32; off; off >>= 1) d += __shfl_xor(d, off, 64);
    scale_s[tid] = sc;
    if (tid == 0) { Ms = M; dens = d; }
  }
  __syncthreads();
  float M = Ms, rden = 1.f / dens;
  float a = 0.f;
  #pragma unroll 8
  for (int c = 0; c < 64; ++c) a += scale_s[c] * numpart[(size_t)(b * 64 + c) * NH + tid];
  xcat0[b * 1280 + 256 + tid] = (_Float16)(a * rden);
  if (tid < 256) xcat0[b * 1280 + tid] = (_Float16)emb[(size_t)token[b] * NE + tid];
  xcat0[b * 1280 + 768 + tid] = (_Float16)h0[b * NH + tid];
  #pragma unroll
  for (int i = 0; i < 4; ++i) {
    int t = tid + (i << 9);
    attw[(b << 11) + t] = __expf(eng[(b << 11) + t] - M) * rden;
  }
}

// ---------- LSTM cell activation (combines gate partials) ----------
__global__ void k_act(const float* __restrict__ pg, const float* __restrict__ bih,
                      const float* __restrict__ bhh, const float* __restrict__ cprev,
                      float* __restrict__ hout, float* __restrict__ cout,
                      _Float16* __restrict__ hf16, int hpitch, int nchunks) {
  int idx = blockIdx.x * 256 + threadIdx.x;   // 0..32767
  int b = idx >> 9, u = idx & 511;
  float g[4];
  #pragma unroll
  for (int gi = 0; gi < 4; ++gi) {
    float s = bih[gi * 512 + u] + bhh[gi * 512 + u];
    for (int kc = 0; kc < nchunks; ++kc)
      s += pg[((size_t)kc * 64 + b) * 2048 + gi * 512 + u];
    g[gi] = s;
  }
  float c = fast_sig(g[1]) * cprev[idx] + fast_sig(g[0]) * fast_tanh(g[2]);
  float h = fast_sig(g[3]) * fast_tanh(c);
  cout[idx] = c;
  hout[idx] = h;
  hf16[b * hpitch + u] = (_Float16)h;
}

// ---------- launch ----------
extern "C" void kernel_launch(void* const* d_in, const int* in_sizes, int n_in,
                              void* d_out, int out_size, void* d_ws, size_t ws_size,
                              hipStream_t stream) {
  (void)in_sizes; (void)n_in; (void)out_size; (void)ws_size;
  const int*   token = (const int*)d_in[0];
  const float* h0    = (const float*)d_in[1];
  const float* c0    = (const float*)d_in[2];
  const float* enc   = (const float*)d_in[3];
  const int*   mask  = (const int*)d_in[4];
  const float* emb   = (const float*)d_in[5];
  const float* Wattn = (const float*)d_in[6];
  const float* battn = (const float*)d_in[7];
  const float* vattn = (const float*)d_in[8];
  const float* Wih0  = (const float*)d_in[9];
  const float* Whh0  = (const float*)d_in[10];
  const float* bih0  = (const float*)d_in[11];
  const float* bhh0  = (const float*)d_in[12];
  const float* Wih1  = (const float*)d_in[13];
  const float* Whh1  = (const float*)d_in[14];
  const float* bih1  = (const float*)d_in[15];
  const float* bhh1  = (const float*)d_in[16];
  const float* Wout  = (const float*)d_in[17];
  const float* bout  = (const float*)d_in[18];

  float* ws    = (float*)d_ws;
  float* pghp  = ws;                       //  2*64*512   = 65536
  float* eng   = pghp + 65536;             //  131072
  float* mcsc  = eng + 131072;             //  8192 (4096 tiles x 2)
  float* np    = mcsc + 8192;              //  4096*512   = 2097152
  float* pg0   = np + 2097152;             //  4*64*2048  = 524288
  float* pg1   = pg0 + 524288;             //  524288
  _Float16* Be    = (_Float16*)(pg1 + 524288);  // 262144 h
  _Float16* xh    = Be + 262144;                // 64*512
  _Float16* xcat0 = xh + 32768;                 // 64*1280
  _Float16* xcat1 = xcat0 + 81920;              // 64*1024
  _Float16* h1f   = xcat1 + 65536;              // 64*512

  float* out    = (float*)d_out;
  float* logits = out;
  float* hnew   = out + (size_t)NB * NV;
  float* cnew   = hnew + 2 * NB * NH;
  float* attw   = cnew + 2 * NB * NH;

  k_swz_be<<<dim3(128), dim3(256), 0, stream>>>(Wattn, Be);
  k_prep_htop<<<dim3(64), dim3(512), 0, stream>>>(h0, xh, xcat1);
  k_gemm_bT<256><<<dim3(32), dim3(128), 0, stream>>>(
      xh, NH, Wattn, 1024, nullptr, 0, 1 << 30, nullptr, pghp, NH);
  k_energy<<<dim3(4096), dim3(256), 0, stream>>>(
      enc, Be, pghp, pghp + 32768, battn, vattn, mask, eng, mcsc, np);
  k_combine<<<dim3(64), dim3(512), 0, stream>>>(
      mcsc, np, eng, token, emb, h0, xcat0, attw);
  k_gemm_bT<320><<<dim3(256), dim3(128), 0, stream>>>(
      xcat0, 1280, Wih0, 768, Whh0, NH, 768, nullptr, pg0, 2048);
  k_act<<<dim3(128), dim3(256), 0, stream>>>(
      pg0, bih0, bhh0, c0, hnew, cnew, xcat1, 1024, 4);
  k_gemm_bT<256><<<dim3(256), dim3(128), 0, stream>>>(
      xcat1, 1024, Wih1, NH, Whh1, NH, NH, nullptr, pg1, 2048);
  k_act<<<dim3(128), dim3(256), 0, stream>>>(
      pg1, bih1, bhh1, c0 + NB * NH, hnew + NB * NH, cnew + NB * NH, h1f, 512, 4);
  k_gemm_bT<512><<<dim3(1000), dim3(128), 0, stream>>>(
      h1f, NH, Wout, NH, nullptr, 0, 1 << 30, bout, logits, NV);
}